// Round 7
// baseline (303.712 us; speedup 1.0000x reference)
//
#include <hip/hip_runtime.h>
#include <hip/hip_fp16.h>
#include <math.h>

// GNO layer, v6:
//   Gp[j,c] = feat[j] @ W1[3:67,c] + b1[c] + coords[j] @ W1[0:3,c]   (fp16)
//   out[i]  = feat[i] @ Ws + bs + b2                                  (skip)
//   hbar_i  = (1/K) sum_k GELU( Gp[idx[i,k]] - coords[i] @ W1[0:3] )
//   out[i] += hbar_i @ W2
//
// v6: phase1 rebuilt spill-proof — weights in LDS as half2{w1,ws}, one
// ds_read_b32 per d amortized over an 8-point group (16 FMAs); 8 feature
// rows in flight; coords via one coalesced 24-float load + readlane.
// Phase2 byte-identical to v5 (attribution).

#define KNN 16

__device__ __forceinline__ float lane_bcast(float v, int lane) {
    return __int_as_float(__builtin_amdgcn_readlane(__float_as_int(v), lane));
}

// gelu(x) ~= x * sigmoid(1.5957691*(x + 0.044715 x^3)); exp2-folded constants.
// max |delta| vs exact erf-GELU ~3e-4.
__device__ __forceinline__ float gelu_fast(float x) {
    const float t = x * fmaf(x * x, -0.10294324f, -2.30220821f); // -z*log2(e)
    return x * __builtin_amdgcn_rcpf(1.0f + exp2f(t));
}

// Fused phase 1 v6: Gp (fp16, coords folded) + skip pre-write into out.
// No per-lane weight arrays -> no spill risk; VGPR ~50.
__global__ __launch_bounds__(256) void gno_phase1(
    const float* __restrict__ features, const float* __restrict__ coords,
    const float* __restrict__ W1, const float* __restrict__ b1,
    const float* __restrict__ Ws, const float* __restrict__ bs,
    const float* __restrict__ b2, __half* __restrict__ Gp,
    float* __restrict__ out, int n)
{
    __shared__ __half2 wlds[64 * 64];   // [d][c] = {W1[3+d][c], Ws[d][c]}, 16 KB
    const int tid = threadIdx.y * 64 + threadIdx.x;
    for (int t = tid; t < 64 * 64; t += 256) {
        const int d = t >> 6, cc = t & 63;
        wlds[t] = __halves2half2(__float2half(W1[(3 + d) * 64 + cc]),
                                 __float2half(Ws[d * 64 + cc]));
    }
    const int c = threadIdx.x;
    const float w1px = W1[c], w1py = W1[64 + c], w1pz = W1[128 + c];
    const float b1c = b1[c];
    const float sbc = bs[c] + b2[c];
    __syncthreads();

    const int wave = blockIdx.x * 4 + threadIdx.y;
    const int nw   = gridDim.x * 4;
    for (int i0 = wave * 8; i0 < n; i0 += nw * 8) {   // n%8==0: no intra-group tail
        // 8 feature rows, issued back-to-back (coalesced 256 B each)
        float f[8];
        #pragma unroll
        for (int p = 0; p < 8; ++p) f[p] = features[(size_t)(i0 + p) * 64 + c];
        // coords for 8 contiguous points = 24 contiguous floats via lanes 0..23
        const float cv = (c < 24) ? coords[(size_t)i0 * 3 + c] : 0.0f;

        float a[8], s[8];
        #pragma unroll
        for (int p = 0; p < 8; ++p) {
            float ax = fmaf(lane_bcast(cv, 3 * p + 0), w1px, b1c);
            ax = fmaf(lane_bcast(cv, 3 * p + 1), w1py, ax);
            ax = fmaf(lane_bcast(cv, 3 * p + 2), w1pz, ax);
            a[p] = ax; s[p] = sbc;
        }
        #pragma unroll 16
        for (int d = 0; d < 64; ++d) {
            const float2 w = __half22float2(wlds[d * 64 + c]);  // 2-way bank alias: free
            #pragma unroll
            for (int p = 0; p < 8; ++p) {
                const float fd = lane_bcast(f[p], d);
                a[p] = fmaf(fd, w.x, a[p]);
                s[p] = fmaf(fd, w.y, s[p]);
            }
        }
        #pragma unroll
        for (int p = 0; p < 8; ++p) {
            Gp[(size_t)(i0 + p) * 64 + c]  = __float2half(a[p]);
            out[(size_t)(i0 + p) * 64 + c] = s[p];
        }
    }
}

// Phase 2: byte-identical to v5 (2 pts/iter, 16 packed gathers, fast GELU).
__global__ __launch_bounds__(256, 6) void gno_phase2(
    const float* __restrict__ coords, const int* __restrict__ idx,
    const float* __restrict__ W1, const float* __restrict__ W2,
    const __half2* __restrict__ Gp2, float* __restrict__ out, int n)
{
    __shared__ float w2s[64 * 64];
    const int tid = threadIdx.y * 64 + threadIdx.x;
    #pragma unroll
    for (int t = 0; t < 16; ++t) w2s[t * 256 + tid] = W2[t * 256 + tid];

    const int c   = threadIdx.x;
    const int m   = c & 31;               // channel-pair id this lane gathers
    const int odd = (c >> 5);             // 0: even-k neighbors, 1: odd-k
    const float wx0 = W1[2 * m],       wx1 = W1[2 * m + 1];
    const float wy0 = W1[64 + 2 * m],  wy1 = W1[64 + 2 * m + 1];
    const float wz0 = W1[128 + 2 * m], wz1 = W1[128 + 2 * m + 1];
    __syncthreads();

    const int wave   = blockIdx.x * 4 + threadIdx.y;
    const int stride = gridDim.x * 4;
    for (int i0 = wave * 2; i0 < n; i0 += stride * 2) {
        const int i1 = i0 + 1;
        const bool has1 = (i1 < n);
        const int vj = idx[i0 * KNN + (c & 31)];

        const float c0x = coords[(size_t)i0 * 3 + 0];
        const float c0y = coords[(size_t)i0 * 3 + 1];
        const float c0z = coords[(size_t)i0 * 3 + 2];
        float P00 = c0x * wx0; P00 = fmaf(c0y, wy0, P00); P00 = fmaf(c0z, wz0, P00);
        float P01 = c0x * wx1; P01 = fmaf(c0y, wy1, P01); P01 = fmaf(c0z, wz1, P01);
        float P10 = 0.f, P11 = 0.f;
        if (has1) {
            const float c1x = coords[(size_t)i1 * 3 + 0];
            const float c1y = coords[(size_t)i1 * 3 + 1];
            const float c1z = coords[(size_t)i1 * 3 + 2];
            P10 = c1x * wx0; P10 = fmaf(c1y, wy0, P10); P10 = fmaf(c1z, wz0, P10);
            P11 = c1x * wx1; P11 = fmaf(c1y, wy1, P11); P11 = fmaf(c1z, wz1, P11);
        }

        __half2 gv[16];
        #pragma unroll
        for (int p = 0; p < 8; ++p) {
            const int se = __builtin_amdgcn_readlane(vj, 2 * p);
            const int so = __builtin_amdgcn_readlane(vj, 2 * p + 1);
            const int row = odd ? so : se;
            gv[p] = Gp2[(size_t)row * 32 + m];
        }
        if (has1) {
            #pragma unroll
            for (int p = 0; p < 8; ++p) {
                const int se = __builtin_amdgcn_readlane(vj, 16 + 2 * p);
                const int so = __builtin_amdgcn_readlane(vj, 17 + 2 * p);
                const int row = odd ? so : se;
                gv[8 + p] = Gp2[(size_t)row * 32 + m];
            }
        }

        float a00 = 0.f, a01 = 0.f, a10 = 0.f, a11 = 0.f;
        #pragma unroll
        for (int p = 0; p < 8; ++p) {
            const float2 xy = __half22float2(gv[p]);
            a00 += gelu_fast(xy.x - P00);
            a01 += gelu_fast(xy.y - P01);
        }
        if (has1) {
            #pragma unroll
            for (int p = 0; p < 8; ++p) {
                const float2 xy = __half22float2(gv[8 + p]);
                a10 += gelu_fast(xy.x - P10);
                a11 += gelu_fast(xy.y - P11);
            }
        }
        a00 *= (1.0f / KNN); a01 *= (1.0f / KNN);
        a10 *= (1.0f / KNN); a11 *= (1.0f / KNN);
        a00 += __shfl_xor(a00, 32, 64);
        a01 += __shfl_xor(a01, 32, 64);
        a10 += __shfl_xor(a10, 32, 64);
        a11 += __shfl_xor(a11, 32, 64);

        float o0 = out[(size_t)i0 * 64 + c];
        float o1 = has1 ? out[(size_t)i1 * 64 + c] : 0.f;
        #pragma unroll
        for (int d = 0; d < 64; ++d) {
            const float w = w2s[d * 64 + c];
            o0 = fmaf(lane_bcast((d & 1) ? a01 : a00, d >> 1), w, o0);
            o1 = fmaf(lane_bcast((d & 1) ? a11 : a10, d >> 1), w, o1);
        }
        out[(size_t)i0 * 64 + c] = o0;
        if (has1) out[(size_t)i1 * 64 + c] = o1;
    }
}

extern "C" void kernel_launch(void* const* d_in, const int* in_sizes, int n_in,
                              void* d_out, int out_size, void* d_ws, size_t ws_size,
                              hipStream_t stream) {
    const float* coords   = (const float*)d_in[0];
    const float* features = (const float*)d_in[1];
    const int*   idx      = (const int*)d_in[2];
    const float* W1       = (const float*)d_in[3];
    const float* b1       = (const float*)d_in[4];
    const float* W2       = (const float*)d_in[5];
    const float* b2       = (const float*)d_in[6];
    const float* Ws       = (const float*)d_in[7];
    const float* bs       = (const float*)d_in[8];
    float* out = (float*)d_out;
    const int n = in_sizes[0] / 3;            // 100000
    __half* Gp = (__half*)d_ws;               // n*64 halfs = 12.8 MB

    dim3 block(64, 4);
    gno_phase1<<<dim3(782),  block, 0, stream>>>(features, coords, W1, b1,
                                                 Ws, bs, b2, Gp, out, n);
    gno_phase2<<<dim3(1536), block, 0, stream>>>(coords, idx, W1, W2,
                                                 (const __half2*)Gp, out, n);
}

// Round 8
// 209.929 us; speedup vs baseline: 1.4467x; 1.4467x over previous
//
#include <hip/hip_runtime.h>
#include <hip/hip_fp16.h>
#include <math.h>

// GNO layer, v7:
//   Gp[j,c] = feat[j] @ W1[3:67,c] + b1[c] + coords[j] @ W1[0:3,c]   (fp16)
//   out[i]  = feat[i] @ Ws + bs + b2                                  (skip)
//   hbar_i  = (1/K) sum_k GELU( Gp[idx[i,k]] - coords[i] @ W1[0:3] )
//   out[i] += hbar_i @ W2
//
// v7: phase1 reverted to v5 (reg-array; round-6 A/B showed LDS variant -17us).
// phase2 epilogue -> MFMA: per 16-point group, hbar staged in wave-private
// XOR-swizzled LDS, 2x ds_read_b128 A-frags, 8x mfma_f32_16x16x32_f16 with
// W2-f16 B-frags preloaded in VGPRs and skip (out) as C-in.

#define KNN 16

typedef _Float16 half8 __attribute__((ext_vector_type(8)));
typedef float float4v __attribute__((ext_vector_type(4)));

__device__ __forceinline__ float lane_bcast(float v, int lane) {
    return __int_as_float(__builtin_amdgcn_readlane(__float_as_int(v), lane));
}

// gelu(x) ~= x * sigmoid(1.5957691*(x + 0.044715 x^3)); exp2-folded constants.
// max |delta| vs exact erf-GELU ~3e-4.
__device__ __forceinline__ float gelu_fast(float x) {
    const float t = x * fmaf(x * x, -0.10294324f, -2.30220821f); // -z*log2(e)
    return x * __builtin_amdgcn_rcpf(1.0f + exp2f(t));
}

// Fused phase 1 (v5 verbatim): Gp (fp16, coords folded) + skip pre-write.
__global__ __launch_bounds__(256) void gno_phase1(
    const float* __restrict__ features, const float* __restrict__ coords,
    const float* __restrict__ W1, const float* __restrict__ b1,
    const float* __restrict__ Ws, const float* __restrict__ bs,
    const float* __restrict__ b2, __half* __restrict__ Gp,
    float* __restrict__ out, int n)
{
    const int c = threadIdx.x;
    float w1r[64], wsr[64];
    #pragma unroll
    for (int d = 0; d < 64; ++d) {
        w1r[d] = W1[(3 + d) * 64 + c];
        wsr[d] = Ws[d * 64 + c];
    }
    const float w1px = W1[c], w1py = W1[64 + c], w1pz = W1[128 + c];
    const float b1c = b1[c];
    const float sbc = bs[c] + b2[c];

    const int wave   = blockIdx.x * 4 + threadIdx.y;
    const int stride = gridDim.x * 4;
    for (int i0 = wave * 2; i0 < n; i0 += stride * 2) {
        const int i1 = i0 + 1;
        const bool has1 = (i1 < n);
        const float f0 = features[(size_t)i0 * 64 + c];
        const float f1 = has1 ? features[(size_t)i1 * 64 + c] : 0.0f;

        float a0 = fmaf(coords[(size_t)i0 * 3 + 0], w1px, b1c);
        a0 = fmaf(coords[(size_t)i0 * 3 + 1], w1py, a0);
        a0 = fmaf(coords[(size_t)i0 * 3 + 2], w1pz, a0);
        float a1 = b1c;
        if (has1) {
            a1 = fmaf(coords[(size_t)i1 * 3 + 0], w1px, a1);
            a1 = fmaf(coords[(size_t)i1 * 3 + 1], w1py, a1);
            a1 = fmaf(coords[(size_t)i1 * 3 + 2], w1pz, a1);
        }
        float s0 = sbc, s1 = sbc;
        #pragma unroll
        for (int d = 0; d < 64; ++d) {
            const float fd0 = lane_bcast(f0, d);
            const float fd1 = lane_bcast(f1, d);
            a0 = fmaf(fd0, w1r[d], a0);
            s0 = fmaf(fd0, wsr[d], s0);
            a1 = fmaf(fd1, w1r[d], a1);
            s1 = fmaf(fd1, wsr[d], s1);
        }
        Gp[(size_t)i0 * 64 + c]  = __float2half(a0);
        out[(size_t)i0 * 64 + c] = s0;
        if (has1) {
            Gp[(size_t)i1 * 64 + c]  = __float2half(a1);
            out[(size_t)i1 * 64 + c] = s1;
        }
    }
}

// Phase 2 v7: v5 gather/GELU front-end + MFMA epilogue per 16-point group.
__global__ __launch_bounds__(256, 4) void gno_phase2(
    const float* __restrict__ coords, const int* __restrict__ idx,
    const float* __restrict__ W1, const float* __restrict__ W2,
    const __half2* __restrict__ Gp2, float* __restrict__ out, int n)
{
    __shared__ unsigned short w2h[4096];        // W2 as f16, staged once
    __shared__ unsigned short hbarall[4][1024]; // per-wave [16 pts][64 ch] f16

    const int tid = threadIdx.y * 64 + threadIdx.x;
    for (int t = tid; t < 4096; t += 256)
        w2h[t] = __half_as_ushort(__float2half(W2[t]));

    const int c   = threadIdx.x;
    const int m   = c & 31;      // channel-pair id this lane gathers
    const int odd = c >> 5;      // 0: even-k neighbors, 1: odd-k
    const int p16 = c & 15;      // MFMA row/col lane coords
    const int l4  = c >> 4;      // 0..3
    const float wx0 = W1[2 * m],       wx1 = W1[2 * m + 1];
    const float wy0 = W1[64 + 2 * m],  wy1 = W1[64 + 2 * m + 1];
    const float wz0 = W1[128 + 2 * m], wz1 = W1[128 + 2 * m + 1];
    __syncthreads();

    // B-fragments for W2: bf[t][h] covers k = h*32 + l4*8 + j, n = t*16 + p16
    half8 bf[4][2];
    #pragma unroll
    for (int t = 0; t < 4; ++t)
        #pragma unroll
        for (int h = 0; h < 2; ++h)
            #pragma unroll
            for (int j = 0; j < 8; ++j)
                bf[t][h][j] = *(const _Float16*)&w2h[(h * 32 + l4 * 8 + j) * 64 + t * 16 + p16];

    unsigned short* hb = hbarall[threadIdx.y];

    const int ngroups = n >> 4;            // n % 16 == 0
    const int gw = blockIdx.x * 4 + threadIdx.y;
    const int nw = gridDim.x * 4;
    for (int g = gw; g < ngroups; g += nw) {
        const int gbase = g << 4;
        #pragma unroll 2
        for (int pp = 0; pp < 8; ++pp) {
            const int i0 = gbase + 2 * pp;
            const int i1 = i0 + 1;
            const int vj = idx[i0 * KNN + (c & 31)];  // 32 lanes = both idx rows

            const float c0x = coords[(size_t)i0 * 3 + 0];
            const float c0y = coords[(size_t)i0 * 3 + 1];
            const float c0z = coords[(size_t)i0 * 3 + 2];
            const float c1x = coords[(size_t)i1 * 3 + 0];
            const float c1y = coords[(size_t)i1 * 3 + 1];
            const float c1z = coords[(size_t)i1 * 3 + 2];
            float P00 = c0x * wx0; P00 = fmaf(c0y, wy0, P00); P00 = fmaf(c0z, wz0, P00);
            float P01 = c0x * wx1; P01 = fmaf(c0y, wy1, P01); P01 = fmaf(c0z, wz1, P01);
            float P10 = c1x * wx0; P10 = fmaf(c1y, wy0, P10); P10 = fmaf(c1z, wz0, P10);
            float P11 = c1x * wx1; P11 = fmaf(c1y, wy1, P11); P11 = fmaf(c1z, wz1, P11);

            // 16 packed gathers (8 per point), issued back-to-back
            __half2 gv[16];
            #pragma unroll
            for (int q = 0; q < 8; ++q) {
                const int se = __builtin_amdgcn_readlane(vj, 2 * q);
                const int so = __builtin_amdgcn_readlane(vj, 2 * q + 1);
                const int row = odd ? so : se;
                gv[q] = Gp2[(size_t)row * 32 + m];
            }
            #pragma unroll
            for (int q = 0; q < 8; ++q) {
                const int se = __builtin_amdgcn_readlane(vj, 16 + 2 * q);
                const int so = __builtin_amdgcn_readlane(vj, 17 + 2 * q);
                const int row = odd ? so : se;
                gv[8 + q] = Gp2[(size_t)row * 32 + m];
            }

            float a00 = 0.f, a01 = 0.f, a10 = 0.f, a11 = 0.f;
            #pragma unroll
            for (int q = 0; q < 8; ++q) {
                const float2 xy = __half22float2(gv[q]);
                a00 += gelu_fast(xy.x - P00);
                a01 += gelu_fast(xy.y - P01);
            }
            #pragma unroll
            for (int q = 0; q < 8; ++q) {
                const float2 xy = __half22float2(gv[8 + q]);
                a10 += gelu_fast(xy.x - P10);
                a11 += gelu_fast(xy.y - P11);
            }
            a00 *= (1.0f / KNN); a01 *= (1.0f / KNN);
            a10 *= (1.0f / KNN); a11 *= (1.0f / KNN);
            a00 += __shfl_xor(a00, 32, 64);
            a01 += __shfl_xor(a01, 32, 64);
            a10 += __shfl_xor(a10, 32, 64);
            a11 += __shfl_xor(a11, 32, 64);

            // lanes<32 own point 2pp (a00,a01); lanes>=32 own 2pp+1 (a10,a11)
            const int lp = 2 * pp + odd;
            const float x0 = odd ? a10 : a00;
            const float x1 = odd ? a11 : a01;
            __half2 hh = __floats2half2_rn(x0, x1);
            int byte = lp * 128 + m * 4;
            byte ^= (lp & 7) << 4;               // XOR swizzle (G4)
            *(unsigned int*)((char*)hb + byte) = *(unsigned int*)&hh;
        }

        // A-fragments: point row p16, k-octet l4*8, k-halves 0/1 (swizzled)
        int b0 = p16 * 128 + l4 * 16;       b0 ^= (p16 & 7) << 4;
        int b1 = p16 * 128 + 64 + l4 * 16;  b1 ^= (p16 & 7) << 4;
        const half8 af0 = *(const half8*)((const char*)hb + b0);
        const half8 af1 = *(const half8*)((const char*)hb + b1);

        // out[16 pts][64] += hbar @ W2 via 8 MFMAs; C-in = skip from phase1
        #pragma unroll
        for (int t = 0; t < 4; ++t) {
            float4v cf;
            #pragma unroll
            for (int j = 0; j < 4; ++j)
                cf[j] = out[(size_t)(gbase + l4 * 4 + j) * 64 + t * 16 + p16];
            float4v d = __builtin_amdgcn_mfma_f32_16x16x32_f16(af0, bf[t][0], cf, 0, 0, 0);
            d = __builtin_amdgcn_mfma_f32_16x16x32_f16(af1, bf[t][1], d, 0, 0, 0);
            #pragma unroll
            for (int j = 0; j < 4; ++j)
                out[(size_t)(gbase + l4 * 4 + j) * 64 + t * 16 + p16] = d[j];
        }
    }
}

extern "C" void kernel_launch(void* const* d_in, const int* in_sizes, int n_in,
                              void* d_out, int out_size, void* d_ws, size_t ws_size,
                              hipStream_t stream) {
    const float* coords   = (const float*)d_in[0];
    const float* features = (const float*)d_in[1];
    const int*   idx      = (const int*)d_in[2];
    const float* W1       = (const float*)d_in[3];
    const float* b1       = (const float*)d_in[4];
    const float* W2       = (const float*)d_in[5];
    const float* b2       = (const float*)d_in[6];
    const float* Ws       = (const float*)d_in[7];
    const float* bs       = (const float*)d_in[8];
    float* out = (float*)d_out;
    const int n = in_sizes[0] / 3;            // 100000
    __half* Gp = (__half*)d_ws;               // n*64 halfs = 12.8 MB

    dim3 block(64, 4);
    gno_phase1<<<dim3(1024), block, 0, stream>>>(features, coords, W1, b1,
                                                 Ws, bs, b2, Gp, out, n);
    gno_phase2<<<dim3(782),  block, 0, stream>>>(coords, idx, W1, W2,
                                                 (const __half2*)Gp, out, n);
}

// Round 9
// 201.748 us; speedup vs baseline: 1.5054x; 1.0405x over previous
//
#include <hip/hip_runtime.h>
#include <hip/hip_fp16.h>
#include <math.h>

// GNO layer, v8:
//   Gp[j,c] = feat[j] @ W1[3:67,c] + b1[c] + coords[j] @ W1[0:3,c]   (fp16)
//   out[i]  = feat[i] @ Ws + bs + b2                                  (skip)
//   hbar_i  = (1/K) sum_k GELU( Gp[idx[i,k]] - coords[i] @ W1[0:3] )
//   out[i] += hbar_i @ W2   (MFMA epilogue, v7-verbatim)
//
// v8: phase2 front-end restructured for memory-level parallelism:
//   - ONE int4 load per 16-point group = all 256 neighbor indices (1 vmcnt
//     wait/group instead of 8); rows via compile-time v_readlane.
//   - coords preloaded once per group into lanes 0..47.
//   - 64 gathers per half-group issued back-to-back before GELU consumes.

#define KNN 16

typedef _Float16 half8 __attribute__((ext_vector_type(8)));
typedef float float4v __attribute__((ext_vector_type(4)));
typedef int int4v __attribute__((ext_vector_type(4)));

__device__ __forceinline__ float lane_bcast(float v, int lane) {
    return __int_as_float(__builtin_amdgcn_readlane(__float_as_int(v), lane));
}

// gelu(x) ~= x * sigmoid(1.5957691*(x + 0.044715 x^3)); exp2-folded constants.
__device__ __forceinline__ float gelu_fast(float x) {
    const float t = x * fmaf(x * x, -0.10294324f, -2.30220821f); // -z*log2(e)
    return x * __builtin_amdgcn_rcpf(1.0f + exp2f(t));
}

// Fused phase 1 (v5 verbatim): Gp (fp16, coords folded) + skip pre-write.
__global__ __launch_bounds__(256) void gno_phase1(
    const float* __restrict__ features, const float* __restrict__ coords,
    const float* __restrict__ W1, const float* __restrict__ b1,
    const float* __restrict__ Ws, const float* __restrict__ bs,
    const float* __restrict__ b2, __half* __restrict__ Gp,
    float* __restrict__ out, int n)
{
    const int c = threadIdx.x;
    float w1r[64], wsr[64];
    #pragma unroll
    for (int d = 0; d < 64; ++d) {
        w1r[d] = W1[(3 + d) * 64 + c];
        wsr[d] = Ws[d * 64 + c];
    }
    const float w1px = W1[c], w1py = W1[64 + c], w1pz = W1[128 + c];
    const float b1c = b1[c];
    const float sbc = bs[c] + b2[c];

    const int wave   = blockIdx.x * 4 + threadIdx.y;
    const int stride = gridDim.x * 4;
    for (int i0 = wave * 2; i0 < n; i0 += stride * 2) {
        const int i1 = i0 + 1;
        const bool has1 = (i1 < n);
        const float f0 = features[(size_t)i0 * 64 + c];
        const float f1 = has1 ? features[(size_t)i1 * 64 + c] : 0.0f;

        float a0 = fmaf(coords[(size_t)i0 * 3 + 0], w1px, b1c);
        a0 = fmaf(coords[(size_t)i0 * 3 + 1], w1py, a0);
        a0 = fmaf(coords[(size_t)i0 * 3 + 2], w1pz, a0);
        float a1 = b1c;
        if (has1) {
            a1 = fmaf(coords[(size_t)i1 * 3 + 0], w1px, a1);
            a1 = fmaf(coords[(size_t)i1 * 3 + 1], w1py, a1);
            a1 = fmaf(coords[(size_t)i1 * 3 + 2], w1pz, a1);
        }
        float s0 = sbc, s1 = sbc;
        #pragma unroll
        for (int d = 0; d < 64; ++d) {
            const float fd0 = lane_bcast(f0, d);
            const float fd1 = lane_bcast(f1, d);
            a0 = fmaf(fd0, w1r[d], a0);
            s0 = fmaf(fd0, wsr[d], s0);
            a1 = fmaf(fd1, w1r[d], a1);
            s1 = fmaf(fd1, wsr[d], s1);
        }
        Gp[(size_t)i0 * 64 + c]  = __float2half(a0);
        out[(size_t)i0 * 64 + c] = s0;
        if (has1) {
            Gp[(size_t)i1 * 64 + c]  = __float2half(a1);
            out[(size_t)i1 * 64 + c] = s1;
        }
    }
}

// Phase 2 v8: group-wide idx/coords preload, 64-deep gather batches,
// MFMA epilogue (v7-verbatim).
__global__ __launch_bounds__(256, 3) void gno_phase2(
    const float* __restrict__ coords, const int* __restrict__ idx,
    const float* __restrict__ W1, const float* __restrict__ W2,
    const __half2* __restrict__ Gp2, float* __restrict__ out, int n)
{
    __shared__ unsigned short w2h[4096];        // W2 as f16
    __shared__ unsigned short hbarall[4][1024]; // per-wave [16 pts][64 ch] f16

    const int tid = threadIdx.y * 64 + threadIdx.x;
    for (int t = tid; t < 4096; t += 256)
        w2h[t] = __half_as_ushort(__float2half(W2[t]));

    const int c   = threadIdx.x;
    const int m   = c & 31;      // channel-pair id this lane gathers
    const int odd = c >> 5;      // 0: even-k neighbors, 1: odd-k
    const int p16 = c & 15;      // MFMA row/col lane coords
    const int l4  = c >> 4;      // 0..3
    const int m4  = m * 4;       // byte offset of channel pair within a row
    const float wx0 = W1[2 * m],       wx1 = W1[2 * m + 1];
    const float wy0 = W1[64 + 2 * m],  wy1 = W1[64 + 2 * m + 1];
    const float wz0 = W1[128 + 2 * m], wz1 = W1[128 + 2 * m + 1];
    __syncthreads();

    // B-fragments for W2: bf[t][h] covers k = h*32 + l4*8 + j, n = t*16 + p16
    half8 bf[4][2];
    #pragma unroll
    for (int t = 0; t < 4; ++t)
        #pragma unroll
        for (int h = 0; h < 2; ++h)
            #pragma unroll
            for (int j = 0; j < 8; ++j)
                bf[t][h][j] = *(const _Float16*)&w2h[(h * 32 + l4 * 8 + j) * 64 + t * 16 + p16];

    unsigned short* hb = hbarall[threadIdx.y];
    const char* gpb = (const char*)Gp2;

    const int ngroups = n >> 4;            // n % 16 == 0
    const int gw = blockIdx.x * 4 + threadIdx.y;
    const int nw = gridDim.x * 4;
    for (int g = gw; g < ngroups; g += nw) {
        const int gbase = g << 4;
        // ALL 256 neighbor indices of this group in one load (4 ints/lane)
        const int4v vj4 = *(const int4v*)(idx + (size_t)gbase * 16 + c * 4);
        // coords of the 16 points: 48 floats in lanes 0..47
        const float cv = (c < 48) ? coords[(size_t)gbase * 3 + c] : 0.0f;

        #pragma unroll
        for (int h = 0; h < 2; ++h) {          // half-group = 8 points
            __half2 gv[4][16];
            // ---- issue all 64 gathers for this half back-to-back ----
            #pragma unroll
            for (int pp = 0; pp < 4; ++pp) {
                const int P2 = h * 4 + pp;     // 2-point block id 0..7
                const int e0 = P2 * 32;        // element base in vj4 stream
                #pragma unroll
                for (int q = 0; q < 8; ++q) {
                    const int ea = e0 + 2 * q,      eb = ea + 1;   // point A
                    const int ec = e0 + 16 + 2 * q, ed = ec + 1;   // point B
                    const int se = __builtin_amdgcn_readlane(vj4[ea & 3], ea >> 2);
                    const int so = __builtin_amdgcn_readlane(vj4[eb & 3], eb >> 2);
                    const int te = __builtin_amdgcn_readlane(vj4[ec & 3], ec >> 2);
                    const int td = __builtin_amdgcn_readlane(vj4[ed & 3], ed >> 2);
                    const int rA = odd ? so : se;
                    const int rB = odd ? td : te;
                    gv[pp][q]     = *(const __half2*)(gpb + (((unsigned)rA << 7) + m4));
                    gv[pp][8 + q] = *(const __half2*)(gpb + (((unsigned)rB << 7) + m4));
                }
            }
            // ---- GELU + reduce + stage, consuming in issue order ----
            #pragma unroll
            for (int pp = 0; pp < 4; ++pp) {
                const int P2  = h * 4 + pp;
                const int lp0 = 2 * P2;
                const float a0x = lane_bcast(cv, 3 * lp0 + 0);
                const float a0y = lane_bcast(cv, 3 * lp0 + 1);
                const float a0z = lane_bcast(cv, 3 * lp0 + 2);
                const float a1x = lane_bcast(cv, 3 * lp0 + 3);
                const float a1y = lane_bcast(cv, 3 * lp0 + 4);
                const float a1z = lane_bcast(cv, 3 * lp0 + 5);
                float P00 = a0x * wx0; P00 = fmaf(a0y, wy0, P00); P00 = fmaf(a0z, wz0, P00);
                float P01 = a0x * wx1; P01 = fmaf(a0y, wy1, P01); P01 = fmaf(a0z, wz1, P01);
                float P10 = a1x * wx0; P10 = fmaf(a1y, wy0, P10); P10 = fmaf(a1z, wz0, P10);
                float P11 = a1x * wx1; P11 = fmaf(a1y, wy1, P11); P11 = fmaf(a1z, wz1, P11);

                float a00 = 0.f, a01 = 0.f, a10 = 0.f, a11 = 0.f;
                #pragma unroll
                for (int q = 0; q < 8; ++q) {
                    const float2 xy = __half22float2(gv[pp][q]);
                    a00 += gelu_fast(xy.x - P00);
                    a01 += gelu_fast(xy.y - P01);
                }
                #pragma unroll
                for (int q = 0; q < 8; ++q) {
                    const float2 xy = __half22float2(gv[pp][8 + q]);
                    a10 += gelu_fast(xy.x - P10);
                    a11 += gelu_fast(xy.y - P11);
                }
                a00 *= (1.0f / KNN); a01 *= (1.0f / KNN);
                a10 *= (1.0f / KNN); a11 *= (1.0f / KNN);
                a00 += __shfl_xor(a00, 32, 64);
                a01 += __shfl_xor(a01, 32, 64);
                a10 += __shfl_xor(a10, 32, 64);
                a11 += __shfl_xor(a11, 32, 64);

                // lanes<32 own point lp0; lanes>=32 own lp0+1
                const int lp = lp0 + odd;
                const float x0 = odd ? a10 : a00;
                const float x1 = odd ? a11 : a01;
                __half2 hh = __floats2half2_rn(x0, x1);
                int byte = lp * 128 + m4;
                byte ^= (lp & 7) << 4;               // XOR swizzle (G4)
                *(unsigned int*)((char*)hb + byte) = *(unsigned int*)&hh;
            }
        }

        // ---- MFMA epilogue (v7-verbatim) ----
        int b0 = p16 * 128 + l4 * 16;       b0 ^= (p16 & 7) << 4;
        int b1 = p16 * 128 + 64 + l4 * 16;  b1 ^= (p16 & 7) << 4;
        const half8 af0 = *(const half8*)((const char*)hb + b0);
        const half8 af1 = *(const half8*)((const char*)hb + b1);

        #pragma unroll
        for (int t = 0; t < 4; ++t) {
            float4v cf;
            #pragma unroll
            for (int j = 0; j < 4; ++j)
                cf[j] = out[(size_t)(gbase + l4 * 4 + j) * 64 + t * 16 + p16];
            float4v d = __builtin_amdgcn_mfma_f32_16x16x32_f16(af0, bf[t][0], cf, 0, 0, 0);
            d = __builtin_amdgcn_mfma_f32_16x16x32_f16(af1, bf[t][1], d, 0, 0, 0);
            #pragma unroll
            for (int j = 0; j < 4; ++j)
                out[(size_t)(gbase + l4 * 4 + j) * 64 + t * 16 + p16] = d[j];
        }
    }
}

extern "C" void kernel_launch(void* const* d_in, const int* in_sizes, int n_in,
                              void* d_out, int out_size, void* d_ws, size_t ws_size,
                              hipStream_t stream) {
    const float* coords   = (const float*)d_in[0];
    const float* features = (const float*)d_in[1];
    const int*   idx      = (const int*)d_in[2];
    const float* W1       = (const float*)d_in[3];
    const float* b1       = (const float*)d_in[4];
    const float* W2       = (const float*)d_in[5];
    const float* b2       = (const float*)d_in[6];
    const float* Ws       = (const float*)d_in[7];
    const float* bs       = (const float*)d_in[8];
    float* out = (float*)d_out;
    const int n = in_sizes[0] / 3;            // 100000
    __half* Gp = (__half*)d_ws;               // n*64 halfs = 12.8 MB

    dim3 block(64, 4);
    gno_phase1<<<dim3(1024), block, 0, stream>>>(features, coords, W1, b1,
                                                 Ws, bs, b2, Gp, out, n);
    gno_phase2<<<dim3(782),  block, 0, stream>>>(coords, idx, W1, W2,
                                                 (const __half2*)Gp, out, n);
}